// Round 5
// baseline (208.849 us; speedup 1.0000x reference)
//
#include <hip/hip_runtime.h>
#include <hip/hip_bf16.h>

#define CRF_B 1024
#define CRF_T 512
#define CRF_C 32
#define DPF 8

typedef float f32x4 __attribute__((ext_vector_type(4)));
typedef short s16x8 __attribute__((ext_vector_type(8)));

// f32 -> bf16 bits, round-nearest-even (init path only)
static __device__ __forceinline__ unsigned f2bf(float f) {
    union { float f; unsigned u; } v; v.f = f;
    return (v.u + 0x7FFFu + ((v.u >> 16) & 1u)) >> 16;
}

#define CVT_PK(dst, lo, hi) \
    asm("v_cvt_pk_bf16_f32 %0, %1, %2" : "=v"(dst) : "v"(lo), "v"(hi))
#define SWAP32(a, b) \
    asm("v_permlane32_swap_b32 %0, %1" : "+v"(a), "+v"(b))
#define SWAP16(a, b) \
    asm("v_permlane16_swap_b32 %0, %1" : "+v"(a), "+v"(b))

// One wave = 16 batch rows. lane l: r = l&15 (batch col), h = l>>4 (0..3).
// State: P[k][r] = exp(alpha[k] - s) as bf16 in MFMA-B layout.
// Step: D = E' x P via 2x mfma_f32_16x16x32_bf16 (A0/A1 static = exp(trans)).
// Output: alpha_t[j] = x_t[j] + sU + log(D);  new state p' = D * exp(x + sU - sC).
// Shifts sU/sC/aQ give the log->shfl 2 steps of slack off the MFMA chain.
// ROUND-5 FIX: prefetch slots are NAMED variables (pl0..pl7/ph0..ph7) with 8
// explicitly-written steps per outer iteration — no array indexing can reach
// scratch (round 4: VGPR=84 proved plo[]/phi[] spilled; ~5x inst inflation).
__global__ __launch_bounds__(64) void crf_fwd_kernel(
    const float* __restrict__ x,      // [B, T, C]
    const float* __restrict__ trans,  // [C, C]
    const float* __restrict__ orig,   // [C]
    float* __restrict__ out)          // [T, B, C]
{
    const int l = threadIdx.x;
    const int r = l & 15;
    const int h = l >> 4;
    const int b = blockIdx.x * 16 + r;

    // ---- static A fragments: E'[j][k] = exp(trans[j][k]) in bf16 ----
    s16x8 A0, A1;
    #pragma unroll
    for (int e = 0; e < 8; ++e) {
        int k = h * 8 + e;
        A0[e] = (short)f2bf(__expf(trans[r * CRF_C + k]));          // j = r
        A1[e] = (short)f2bf(__expf(trans[(16 + r) * CRF_C + k]));   // j = 16+r
    }

    const float* xb = x + (size_t)b * CRF_T * CRF_C;   // x[b][t][c]

    // ---- t = 0 init ----
    float s0 = xb[0] + orig[0];                        // alpha_0[0]

    f32x4 ib0 = *(const f32x4*)(xb + 8 * h);
    f32x4 ib1 = *(const f32x4*)(xb + 8 * h + 4);
    f32x4 ob0 = *(const f32x4*)(orig + 8 * h);
    f32x4 ob1 = *(const f32x4*)(orig + 8 * h + 4);
    unsigned q0, q1, q2, q3;
    CVT_PK(q0, __expf(ib0[0] + ob0[0] - s0), __expf(ib0[1] + ob0[1] - s0));
    CVT_PK(q1, __expf(ib0[2] + ob0[2] - s0), __expf(ib0[3] + ob0[3] - s0));
    CVT_PK(q2, __expf(ib1[0] + ob1[0] - s0), __expf(ib1[1] + ob1[1] - s0));
    CVT_PK(q3, __expf(ib1[2] + ob1[2] - s0), __expf(ib1[3] + ob1[3] - s0));
    s16x8 Bf;
    {
        union { unsigned w[4]; s16x8 v; } bu;
        bu.w[0] = q0; bu.w[1] = q1; bu.w[2] = q2; bu.w[3] = q3;
        Bf = bu.v;
    }

    // t = 0 outputs (D-layout j positions)
    {
        f32x4 xd0 = *(const f32x4*)(xb + 4 * h);
        f32x4 xd1 = *(const f32x4*)(xb + 16 + 4 * h);
        f32x4 od0 = *(const f32x4*)(orig + 4 * h);
        f32x4 od1 = *(const f32x4*)(orig + 16 + 4 * h);
        f32x4 a00, a01;
        #pragma unroll
        for (int i = 0; i < 4; ++i) { a00[i] = xd0[i] + od0[i]; a01[i] = xd1[i] + od1[i]; }
        *(f32x4*)(out + (size_t)b * CRF_C + 4 * h) = a00;
        *(f32x4*)(out + (size_t)b * CRF_C + 16 + 4 * h) = a01;
    }

    // ---- emission prefetch: NAMED slots, slot d holds t = 1+d ----
#define LOADSLOT(PL_, PH_, TT_) \
    { const float* pa_ = xb + (size_t)(TT_) * CRF_C; \
      PL_ = *(const f32x4*)(pa_ + 4 * h); \
      PH_ = *(const f32x4*)(pa_ + 16 + 4 * h); }

    f32x4 pl0, pl1, pl2, pl3, pl4, pl5, pl6, pl7;
    f32x4 ph0, ph1, ph2, ph3, ph4, ph5, ph6, ph7;
    LOADSLOT(pl0, ph0, 1) LOADSLOT(pl1, ph1, 2)
    LOADSLOT(pl2, ph2, 3) LOADSLOT(pl3, ph3, 4)
    LOADSLOT(pl4, ph4, 5) LOADSLOT(pl5, ph5, 6)
    LOADSLOT(pl6, ph6, 7) LOADSLOT(pl7, ph7, 8)

    const f32x4 zz = {0.f, 0.f, 0.f, 0.f};
    float sU = s0, sC = s0, aQ = s0;
    float* op0 = out + ((size_t)CRF_B + b) * CRF_C + 4 * h;   // t=1 row

#define STEP(T_, PL_, PH_, REFILL_)                                            \
    {                                                                          \
        f32x4 xl = PL_, xh = PH_;                                              \
        if (REFILL_) {                                                         \
            int tn_ = (T_) + DPF; if (tn_ > CRF_T - 1) tn_ = CRF_T - 1;        \
            LOADSLOT(PL_, PH_, tn_)                                            \
        }                                                                      \
        f32x4 D0 = __builtin_amdgcn_mfma_f32_16x16x32_bf16(A0, Bf, zz, 0, 0, 0); \
        f32x4 D1 = __builtin_amdgcn_mfma_f32_16x16x32_bf16(A1, Bf, zz, 0, 0, 0); \
        float dlt = sU - sC;                                                   \
        float f0 = __expf(xl[0] + dlt), f1 = __expf(xl[1] + dlt);              \
        float f2 = __expf(xl[2] + dlt), f3 = __expf(xl[3] + dlt);              \
        float g0 = __expf(xh[0] + dlt), g1 = __expf(xh[1] + dlt);              \
        float g2 = __expf(xh[2] + dlt), g3 = __expf(xh[3] + dlt);              \
        f32x4 alo, ahi;                                                        \
        alo[0] = xl[0] + sU + __logf(D0[0]);                                   \
        alo[1] = xl[1] + sU + __logf(D0[1]);                                   \
        alo[2] = xl[2] + sU + __logf(D0[2]);                                   \
        alo[3] = xl[3] + sU + __logf(D0[3]);                                   \
        ahi[0] = xh[0] + sU + __logf(D1[0]);                                   \
        ahi[1] = xh[1] + sU + __logf(D1[1]);                                   \
        ahi[2] = xh[2] + sU + __logf(D1[2]);                                   \
        ahi[3] = xh[3] + sU + __logf(D1[3]);                                   \
        *(f32x4*)op0 = alo;                                                    \
        *(f32x4*)(op0 + 16) = ahi;                                             \
        op0 += CRF_B * CRF_C;                                                  \
        float a0new = __shfl(alo[0], r, 64);                                   \
        unsigned w0, w1, w2, w3;                                               \
        CVT_PK(w0, D0[0] * f0, D0[1] * f1);                                    \
        CVT_PK(w1, D0[2] * f2, D0[3] * f3);                                    \
        CVT_PK(w2, D1[0] * g0, D1[1] * g1);                                    \
        CVT_PK(w3, D1[2] * g2, D1[3] * g3);                                    \
        SWAP32(w0, w2); SWAP16(w0, w2);                                        \
        SWAP32(w1, w3); SWAP16(w1, w3);                                        \
        {                                                                      \
            union { unsigned w[4]; s16x8 v; } bu_;                             \
            bu_.w[0] = w0; bu_.w[1] = w1; bu_.w[2] = w2; bu_.w[3] = w3;        \
            Bf = bu_.v;                                                        \
        }                                                                      \
        sU = sC; sC = aQ; aQ = a0new;                                          \
    }

    int t = 1;
    for (int tb = 0; tb < 63; ++tb) {          // t = 1 .. 504
        STEP(t, pl0, ph0, 1) ++t;
        STEP(t, pl1, ph1, 1) ++t;
        STEP(t, pl2, ph2, 1) ++t;
        STEP(t, pl3, ph3, 1) ++t;
        STEP(t, pl4, ph4, 1) ++t;
        STEP(t, pl5, ph5, 1) ++t;
        STEP(t, pl6, ph6, 1) ++t;
        STEP(t, pl7, ph7, 1) ++t;
    }
    // tail: t = 505 .. 511, no refill
    STEP(t, pl0, ph0, 0) ++t;
    STEP(t, pl1, ph1, 0) ++t;
    STEP(t, pl2, ph2, 0) ++t;
    STEP(t, pl3, ph3, 0) ++t;
    STEP(t, pl4, ph4, 0) ++t;
    STEP(t, pl5, ph5, 0) ++t;
    STEP(t, pl6, ph6, 0) ++t;
#undef STEP
#undef LOADSLOT
}

extern "C" void kernel_launch(void* const* d_in, const int* in_sizes, int n_in,
                              void* d_out, int out_size, void* d_ws, size_t ws_size,
                              hipStream_t stream) {
    const float* pad_x = (const float*)d_in[0];
    const float* trans = (const float*)d_in[1];
    const float* orig  = (const float*)d_in[2];
    float* out = (float*)d_out;

    crf_fwd_kernel<<<dim3(CRF_B / 16), dim3(64), 0, stream>>>(pad_x, trans, orig, out);
}

// Round 6
// 63.178 us; speedup vs baseline: 3.3057x; 3.3057x over previous
//
#include <hip/hip_runtime.h>
#include <hip/hip_bf16.h>

#define CRF_B 1024
#define CRF_T 512
#define CRF_C 32
#define WARM 16

typedef float f32x4 __attribute__((ext_vector_type(4)));
typedef short s16x8 __attribute__((ext_vector_type(8)));

// f32 -> bf16 bits, round-nearest-even (init/const path only)
static __device__ __forceinline__ unsigned f2bf(float f) {
    union { float f; unsigned u; } v; v.f = f;
    return (v.u + 0x7FFFu + ((v.u >> 16) & 1u)) >> 16;
}

#define CVT_PK(dst, lo, hi) \
    asm("v_cvt_pk_bf16_f32 %0, %1, %2" : "=v"(dst) : "v"(lo), "v"(hi))
#define SWAP32(a, b) \
    asm("v_permlane32_swap_b32 %0, %1" : "+v"(a), "+v"(b))
#define SWAP16(a, b) \
    asm("v_permlane16_swap_b32 %0, %1" : "+v"(a), "+v"(b))

#define MAKE_AFRAGS()                                                          \
    s16x8 A0, A1;                                                              \
    _Pragma("unroll")                                                          \
    for (int e = 0; e < 8; ++e) {                                              \
        int k_ = h * 8 + e;                                                    \
        A0[e] = (short)f2bf(__expf(trans[r * CRF_C + k_]));                    \
        A1[e] = (short)f2bf(__expf(trans[(16 + r) * CRF_C + k_]));             \
    }

#define LOADSLOT(PL_, PH_, TT_)                                                \
    { const float* pa_ = xb + (size_t)(TT_) * CRF_C;                           \
      PL_ = *(const f32x4*)(pa_ + 4 * h);                                      \
      PH_ = *(const f32x4*)(pa_ + 16 + 4 * h); }

// ============================================================================
// Pass 1: per (batch, segment) run spec chain from flat init at L*s-WARM
// (s=0: exact init at t=0). Exponent-based rescale, no on-chain logs.
// Stores ws_v[(b*S+s)*32 + j] = spec alpha at t = L*s-1 (s>0), and
// ws_u[b*S+s] = spec alpha[L*(s+1)-1][0].
// ============================================================================
__global__ __launch_bounds__(64) void crf_seam_kernel(
    const float* __restrict__ x, const float* __restrict__ trans,
    const float* __restrict__ orig, float* __restrict__ ws_v,
    float* __restrict__ ws_u, int S, int L)
{
    const int l = threadIdx.x;
    const int r = l & 15;
    const int h = l >> 4;
    const int b = blockIdx.x * 16 + r;
    const int s = blockIdx.y;

    MAKE_AFRAGS();

    const float* xb = x + (size_t)b * CRF_T * CRF_C;
    const int t_a = (s == 0) ? 0 : (L * s - WARM);

    // init state at t_a (B-layout rows 8h..8h+7)
    float base0;
    f32x4 ab0, ab1;
    {
        const float* row = xb + (size_t)t_a * CRF_C;
        ab0 = *(const f32x4*)(row + 8 * h);
        ab1 = *(const f32x4*)(row + 8 * h + 4);
        if (s == 0) {
            f32x4 ob0 = *(const f32x4*)(orig + 8 * h);
            f32x4 ob1 = *(const f32x4*)(orig + 8 * h + 4);
            #pragma unroll
            for (int i = 0; i < 4; ++i) { ab0[i] += ob0[i]; ab1[i] += ob1[i]; }
            base0 = row[0] + orig[0];
        } else {
            base0 = row[0];
        }
    }
    float A = base0;   // log-scale accumulator: alpha ~= log(p) + A
    s16x8 Bf;
    {
        unsigned q0, q1, q2, q3;
        CVT_PK(q0, __expf(ab0[0] - base0), __expf(ab0[1] - base0));
        CVT_PK(q1, __expf(ab0[2] - base0), __expf(ab0[3] - base0));
        CVT_PK(q2, __expf(ab1[0] - base0), __expf(ab1[1] - base0));
        CVT_PK(q3, __expf(ab1[2] - base0), __expf(ab1[3] - base0));
        union { unsigned w[4]; s16x8 v; } bu;
        bu.w[0] = q0; bu.w[1] = q1; bu.w[2] = q2; bu.w[3] = q3;
        Bf = bu.v;
    }

    f32x4 pl0, pl1, pl2, pl3, qh0, qh1, qh2, qh3;
    LOADSLOT(pl0, qh0, t_a + 1) LOADSLOT(pl1, qh1, t_a + 2)
    LOADSLOT(pl2, qh2, t_a + 3) LOADSLOT(pl3, qh3, t_a + 4)

    const f32x4 zz = {0.f, 0.f, 0.f, 0.f};
    const int nsteps = (s == 0) ? (L - 1) : (L + WARM - 1);
    int t = t_a + 1, k = 1;
    float uval = 0.0f;
    float* vrow = ws_v + ((size_t)b * S + s) * CRF_C;

#define PSTEP(PL_, PH_)                                                        \
    {                                                                          \
        f32x4 xl = PL_, xh = PH_;                                              \
        { int tn_ = t + 4; if (tn_ > CRF_T - 1) tn_ = CRF_T - 1;               \
          LOADSLOT(PL_, PH_, tn_) }                                            \
        f32x4 D0 = __builtin_amdgcn_mfma_f32_16x16x32_bf16(A0, Bf, zz, 0, 0, 0); \
        f32x4 D1 = __builtin_amdgcn_mfma_f32_16x16x32_bf16(A1, Bf, zz, 0, 0, 0); \
        int ex = (int)((__float_as_uint(D0[0]) >> 23) & 0xFFu) - 127;          \
        ex = __shfl(ex, r, 64);             /* exponent of col's row 0 */      \
        float me = (float)ex;                                                  \
        float Aent = A;                                                        \
        A = Aent + me * 0.69314718055994530942f;                               \
        float f0 = exp2f(fmaf(xl[0], 1.44269504088896f, -me));                 \
        float f1 = exp2f(fmaf(xl[1], 1.44269504088896f, -me));                 \
        float f2 = exp2f(fmaf(xl[2], 1.44269504088896f, -me));                 \
        float f3 = exp2f(fmaf(xl[3], 1.44269504088896f, -me));                 \
        float g0 = exp2f(fmaf(xh[0], 1.44269504088896f, -me));                 \
        float g1 = exp2f(fmaf(xh[1], 1.44269504088896f, -me));                 \
        float g2 = exp2f(fmaf(xh[2], 1.44269504088896f, -me));                 \
        float g3 = exp2f(fmaf(xh[3], 1.44269504088896f, -me));                 \
        uval = xl[0] + Aent + __logf(D0[0]);                                   \
        if ((k == WARM - 1) && (s != 0)) {   /* seam: t == L*s - 1 */          \
            f32x4 vlo, vhi;                                                    \
            vlo[0] = xl[0] + Aent + __logf(D0[0]);                             \
            vlo[1] = xl[1] + Aent + __logf(D0[1]);                             \
            vlo[2] = xl[2] + Aent + __logf(D0[2]);                             \
            vlo[3] = xl[3] + Aent + __logf(D0[3]);                             \
            vhi[0] = xh[0] + Aent + __logf(D1[0]);                             \
            vhi[1] = xh[1] + Aent + __logf(D1[1]);                             \
            vhi[2] = xh[2] + Aent + __logf(D1[2]);                             \
            vhi[3] = xh[3] + Aent + __logf(D1[3]);                             \
            *(f32x4*)(vrow + 4 * h) = vlo;                                     \
            *(f32x4*)(vrow + 16 + 4 * h) = vhi;                                \
        }                                                                      \
        unsigned w0, w1, w2, w3;                                               \
        CVT_PK(w0, D0[0] * f0, D0[1] * f1);                                    \
        CVT_PK(w1, D0[2] * f2, D0[3] * f3);                                    \
        CVT_PK(w2, D1[0] * g0, D1[1] * g1);                                    \
        CVT_PK(w3, D1[2] * g2, D1[3] * g3);                                    \
        SWAP32(w0, w2); SWAP16(w0, w2);                                        \
        SWAP32(w1, w3); SWAP16(w1, w3);                                        \
        {                                                                      \
            union { unsigned w[4]; s16x8 v; } bu_;                             \
            bu_.w[0] = w0; bu_.w[1] = w1; bu_.w[2] = w2; bu_.w[3] = w3;        \
            Bf = bu_.v;                                                        \
        }                                                                      \
        ++t; ++k;                                                              \
    }

    const int ngr = nsteps >> 2;   // nsteps is always 3 (mod 4) here
    for (int g = 0; g < ngr; ++g) {
        PSTEP(pl0, qh0) PSTEP(pl1, qh1) PSTEP(pl2, qh2) PSTEP(pl3, qh3)
    }
    PSTEP(pl0, qh0) PSTEP(pl1, qh1) PSTEP(pl2, qh2)
#undef PSTEP

    if (h == 0) ws_u[(size_t)b * S + s] = uval;
}

// ============================================================================
// Pass 2: per-batch serial stitch of segment offset constants.
// c_0 = 0;  c_{s} = c_{s-1} + u_{s-1} - v_s[0]
// ============================================================================
__global__ __launch_bounds__(64) void crf_stitch_kernel(
    const float* __restrict__ ws_v, const float* __restrict__ ws_u,
    float* __restrict__ ws_c, int S)
{
    int b = blockIdx.x * 64 + threadIdx.x;
    float c = 0.0f;
    ws_c[(size_t)b * S] = 0.0f;
    for (int s = 1; s < S; ++s) {
        c += ws_u[(size_t)b * S + s - 1] - ws_v[((size_t)b * S + s) * CRF_C];
        ws_c[(size_t)b * S + s] = c;
    }
}

// ============================================================================
// Pass 3: per (batch, segment) exact outputs; init from v_s + c_s (s>0) or
// x[0]+orig (s=0). STEP is round-5's validated step verbatim (DPF=4).
// ============================================================================
__global__ __launch_bounds__(64) void crf_out_kernel(
    const float* __restrict__ x, const float* __restrict__ trans,
    const float* __restrict__ orig, const float* __restrict__ ws_v,
    const float* __restrict__ ws_c, float* __restrict__ out, int S, int L)
{
    const int l = threadIdx.x;
    const int r = l & 15;
    const int h = l >> 4;
    const int b = blockIdx.x * 16 + r;
    const int s = blockIdx.y;

    MAKE_AFRAGS();

    const float* xb = x + (size_t)b * CRF_T * CRF_C;

    int t0;
    float s0;
    s16x8 Bf;
    if (s == 0) {
        t0 = 1;
        s0 = xb[0] + orig[0];
        f32x4 ib0 = *(const f32x4*)(xb + 8 * h);
        f32x4 ib1 = *(const f32x4*)(xb + 8 * h + 4);
        f32x4 ob0 = *(const f32x4*)(orig + 8 * h);
        f32x4 ob1 = *(const f32x4*)(orig + 8 * h + 4);
        unsigned q0, q1, q2, q3;
        CVT_PK(q0, __expf(ib0[0] + ob0[0] - s0), __expf(ib0[1] + ob0[1] - s0));
        CVT_PK(q1, __expf(ib0[2] + ob0[2] - s0), __expf(ib0[3] + ob0[3] - s0));
        CVT_PK(q2, __expf(ib1[0] + ob1[0] - s0), __expf(ib1[1] + ob1[1] - s0));
        CVT_PK(q3, __expf(ib1[2] + ob1[2] - s0), __expf(ib1[3] + ob1[3] - s0));
        union { unsigned w[4]; s16x8 v; } bu;
        bu.w[0] = q0; bu.w[1] = q1; bu.w[2] = q2; bu.w[3] = q3;
        Bf = bu.v;
        // t = 0 outputs (D-layout)
        f32x4 xd0 = *(const f32x4*)(xb + 4 * h);
        f32x4 xd1 = *(const f32x4*)(xb + 16 + 4 * h);
        f32x4 od0 = *(const f32x4*)(orig + 4 * h);
        f32x4 od1 = *(const f32x4*)(orig + 16 + 4 * h);
        f32x4 a00, a01;
        #pragma unroll
        for (int i = 0; i < 4; ++i) { a00[i] = xd0[i] + od0[i]; a01[i] = xd1[i] + od1[i]; }
        *(f32x4*)(out + (size_t)b * CRF_C + 4 * h) = a00;
        *(f32x4*)(out + (size_t)b * CRF_C + 16 + 4 * h) = a01;
    } else {
        t0 = L * s;
        const float* vp = ws_v + ((size_t)b * S + s) * CRF_C;
        float cc = ws_c[(size_t)b * S + s];
        s0 = vp[0] + cc;
        f32x4 vb0 = *(const f32x4*)(vp + 8 * h);
        f32x4 vb1 = *(const f32x4*)(vp + 8 * h + 4);
        unsigned q0, q1, q2, q3;
        CVT_PK(q0, __expf(vb0[0] + cc - s0), __expf(vb0[1] + cc - s0));
        CVT_PK(q1, __expf(vb0[2] + cc - s0), __expf(vb0[3] + cc - s0));
        CVT_PK(q2, __expf(vb1[0] + cc - s0), __expf(vb1[1] + cc - s0));
        CVT_PK(q3, __expf(vb1[2] + cc - s0), __expf(vb1[3] + cc - s0));
        union { unsigned w[4]; s16x8 v; } bu;
        bu.w[0] = q0; bu.w[1] = q1; bu.w[2] = q2; bu.w[3] = q3;
        Bf = bu.v;
    }

    f32x4 pl0, pl1, pl2, pl3, qh0, qh1, qh2, qh3;
    LOADSLOT(pl0, qh0, t0)     LOADSLOT(pl1, qh1, t0 + 1)
    LOADSLOT(pl2, qh2, t0 + 2) LOADSLOT(pl3, qh3, t0 + 3)

    const f32x4 zz = {0.f, 0.f, 0.f, 0.f};
    float sU = s0, sC = s0, aQ = s0;
    float* op0 = out + ((size_t)t0 * CRF_B + b) * CRF_C + 4 * h;
    int t = t0;
    const int nsteps = (s == 0) ? (L - 1) : L;

#define STEP(PL_, PH_)                                                         \
    {                                                                          \
        f32x4 xl = PL_, xh = PH_;                                              \
        { int tn_ = t + 4; if (tn_ > CRF_T - 1) tn_ = CRF_T - 1;               \
          LOADSLOT(PL_, PH_, tn_) }                                            \
        f32x4 D0 = __builtin_amdgcn_mfma_f32_16x16x32_bf16(A0, Bf, zz, 0, 0, 0); \
        f32x4 D1 = __builtin_amdgcn_mfma_f32_16x16x32_bf16(A1, Bf, zz, 0, 0, 0); \
        float dlt = sU - sC;                                                   \
        float f0 = __expf(xl[0] + dlt), f1 = __expf(xl[1] + dlt);              \
        float f2 = __expf(xl[2] + dlt), f3 = __expf(xl[3] + dlt);              \
        float g0 = __expf(xh[0] + dlt), g1 = __expf(xh[1] + dlt);              \
        float g2 = __expf(xh[2] + dlt), g3 = __expf(xh[3] + dlt);              \
        f32x4 alo, ahi;                                                        \
        alo[0] = xl[0] + sU + __logf(D0[0]);                                   \
        alo[1] = xl[1] + sU + __logf(D0[1]);                                   \
        alo[2] = xl[2] + sU + __logf(D0[2]);                                   \
        alo[3] = xl[3] + sU + __logf(D0[3]);                                   \
        ahi[0] = xh[0] + sU + __logf(D1[0]);                                   \
        ahi[1] = xh[1] + sU + __logf(D1[1]);                                   \
        ahi[2] = xh[2] + sU + __logf(D1[2]);                                   \
        ahi[3] = xh[3] + sU + __logf(D1[3]);                                   \
        *(f32x4*)op0 = alo;                                                    \
        *(f32x4*)(op0 + 16) = ahi;                                             \
        op0 += (size_t)CRF_B * CRF_C;                                          \
        float a0new = __shfl(alo[0], r, 64);                                   \
        unsigned w0, w1, w2, w3;                                               \
        CVT_PK(w0, D0[0] * f0, D0[1] * f1);                                    \
        CVT_PK(w1, D0[2] * f2, D0[3] * f3);                                    \
        CVT_PK(w2, D1[0] * g0, D1[1] * g1);                                    \
        CVT_PK(w3, D1[2] * g2, D1[3] * g3);                                    \
        SWAP32(w0, w2); SWAP16(w0, w2);                                        \
        SWAP32(w1, w3); SWAP16(w1, w3);                                        \
        {                                                                      \
            union { unsigned w[4]; s16x8 v; } bu_;                             \
            bu_.w[0] = w0; bu_.w[1] = w1; bu_.w[2] = w2; bu_.w[3] = w3;        \
            Bf = bu_.v;                                                        \
        }                                                                      \
        sU = sC; sC = aQ; aQ = a0new;                                          \
        ++t;                                                                   \
    }

    const int ngr = nsteps >> 2;
    for (int g = 0; g < ngr; ++g) {
        STEP(pl0, qh0) STEP(pl1, qh1) STEP(pl2, qh2) STEP(pl3, qh3)
    }
    if (nsteps & 3) {   // tail is 0 or 3
        STEP(pl0, qh0) STEP(pl1, qh1) STEP(pl2, qh2)
    }
#undef STEP
}

// ============================================================================
// Fallback (round-5 single-kernel, validated) — used only if ws too small.
// ============================================================================
__global__ __launch_bounds__(64) void crf_fwd_fallback(
    const float* __restrict__ x, const float* __restrict__ trans,
    const float* __restrict__ orig, float* __restrict__ out)
{
    const int l = threadIdx.x;
    const int r = l & 15;
    const int h = l >> 4;
    const int b = blockIdx.x * 16 + r;

    MAKE_AFRAGS();

    const float* xb = x + (size_t)b * CRF_T * CRF_C;
    float s0 = xb[0] + orig[0];

    f32x4 ib0 = *(const f32x4*)(xb + 8 * h);
    f32x4 ib1 = *(const f32x4*)(xb + 8 * h + 4);
    f32x4 ob0 = *(const f32x4*)(orig + 8 * h);
    f32x4 ob1 = *(const f32x4*)(orig + 8 * h + 4);
    unsigned q0, q1, q2, q3;
    CVT_PK(q0, __expf(ib0[0] + ob0[0] - s0), __expf(ib0[1] + ob0[1] - s0));
    CVT_PK(q1, __expf(ib0[2] + ob0[2] - s0), __expf(ib0[3] + ob0[3] - s0));
    CVT_PK(q2, __expf(ib1[0] + ob1[0] - s0), __expf(ib1[1] + ob1[1] - s0));
    CVT_PK(q3, __expf(ib1[2] + ob1[2] - s0), __expf(ib1[3] + ob1[3] - s0));
    s16x8 Bf;
    {
        union { unsigned w[4]; s16x8 v; } bu;
        bu.w[0] = q0; bu.w[1] = q1; bu.w[2] = q2; bu.w[3] = q3;
        Bf = bu.v;
    }
    {
        f32x4 xd0 = *(const f32x4*)(xb + 4 * h);
        f32x4 xd1 = *(const f32x4*)(xb + 16 + 4 * h);
        f32x4 od0 = *(const f32x4*)(orig + 4 * h);
        f32x4 od1 = *(const f32x4*)(orig + 16 + 4 * h);
        f32x4 a00, a01;
        #pragma unroll
        for (int i = 0; i < 4; ++i) { a00[i] = xd0[i] + od0[i]; a01[i] = xd1[i] + od1[i]; }
        *(f32x4*)(out + (size_t)b * CRF_C + 4 * h) = a00;
        *(f32x4*)(out + (size_t)b * CRF_C + 16 + 4 * h) = a01;
    }

    f32x4 pl0, pl1, pl2, pl3, qh0, qh1, qh2, qh3;
    LOADSLOT(pl0, qh0, 1) LOADSLOT(pl1, qh1, 2)
    LOADSLOT(pl2, qh2, 3) LOADSLOT(pl3, qh3, 4)

    const f32x4 zz = {0.f, 0.f, 0.f, 0.f};
    float sU = s0, sC = s0, aQ = s0;
    float* op0 = out + ((size_t)CRF_B + b) * CRF_C + 4 * h;
    int t = 1;

#define STEP(PL_, PH_)                                                         \
    {                                                                          \
        f32x4 xl = PL_, xh = PH_;                                              \
        { int tn_ = t + 4; if (tn_ > CRF_T - 1) tn_ = CRF_T - 1;               \
          LOADSLOT(PL_, PH_, tn_) }                                            \
        f32x4 D0 = __builtin_amdgcn_mfma_f32_16x16x32_bf16(A0, Bf, zz, 0, 0, 0); \
        f32x4 D1 = __builtin_amdgcn_mfma_f32_16x16x32_bf16(A1, Bf, zz, 0, 0, 0); \
        float dlt = sU - sC;                                                   \
        float f0 = __expf(xl[0] + dlt), f1 = __expf(xl[1] + dlt);              \
        float f2 = __expf(xl[2] + dlt), f3 = __expf(xl[3] + dlt);              \
        float g0 = __expf(xh[0] + dlt), g1 = __expf(xh[1] + dlt);              \
        float g2 = __expf(xh[2] + dlt), g3 = __expf(xh[3] + dlt);              \
        f32x4 alo, ahi;                                                        \
        alo[0] = xl[0] + sU + __logf(D0[0]);                                   \
        alo[1] = xl[1] + sU + __logf(D0[1]);                                   \
        alo[2] = xl[2] + sU + __logf(D0[2]);                                   \
        alo[3] = xl[3] + sU + __logf(D0[3]);                                   \
        ahi[0] = xh[0] + sU + __logf(D1[0]);                                   \
        ahi[1] = xh[1] + sU + __logf(D1[1]);                                   \
        ahi[2] = xh[2] + sU + __logf(D1[2]);                                   \
        ahi[3] = xh[3] + sU + __logf(D1[3]);                                   \
        *(f32x4*)op0 = alo;                                                    \
        *(f32x4*)(op0 + 16) = ahi;                                             \
        op0 += (size_t)CRF_B * CRF_C;                                          \
        float a0new = __shfl(alo[0], r, 64);                                   \
        unsigned w0, w1, w2, w3;                                               \
        CVT_PK(w0, D0[0] * f0, D0[1] * f1);                                    \
        CVT_PK(w1, D0[2] * f2, D0[3] * f3);                                    \
        CVT_PK(w2, D1[0] * g0, D1[1] * g1);                                    \
        CVT_PK(w3, D1[2] * g2, D1[3] * g3);                                    \
        SWAP32(w0, w2); SWAP16(w0, w2);                                        \
        SWAP32(w1, w3); SWAP16(w1, w3);                                        \
        {                                                                      \
            union { unsigned w[4]; s16x8 v; } bu_;                             \
            bu_.w[0] = w0; bu_.w[1] = w1; bu_.w[2] = w2; bu_.w[3] = w3;        \
            Bf = bu_.v;                                                        \
        }                                                                      \
        sU = sC; sC = aQ; aQ = a0new;                                          \
        ++t;                                                                   \
    }

    for (int g = 0; g < 127; ++g) {   // 508 steps
        STEP(pl0, qh0) STEP(pl1, qh1) STEP(pl2, qh2) STEP(pl3, qh3)
    }
    STEP(pl0, qh0) STEP(pl1, qh1) STEP(pl2, qh2)   // 511 total
#undef STEP
}

extern "C" void kernel_launch(void* const* d_in, const int* in_sizes, int n_in,
                              void* d_out, int out_size, void* d_ws, size_t ws_size,
                              hipStream_t stream) {
    const float* pad_x = (const float*)d_in[0];
    const float* trans = (const float*)d_in[1];
    const float* orig  = (const float*)d_in[2];
    float* out = (float*)d_out;

    auto need = [](int S) {
        return (size_t)CRF_B * S * (CRF_C + 2) * sizeof(float);
    };
    int S = 0;
    if (ws_size >= need(32))      S = 32;
    else if (ws_size >= need(16)) S = 16;
    else if (ws_size >= need(8))  S = 8;

    if (S == 0) {
        crf_fwd_fallback<<<dim3(CRF_B / 16), dim3(64), 0, stream>>>(
            pad_x, trans, orig, out);
        return;
    }
    const int L = CRF_T / S;
    float* ws_v = (float*)d_ws;
    float* ws_u = ws_v + (size_t)CRF_B * S * CRF_C;
    float* ws_c = ws_u + (size_t)CRF_B * S;

    crf_seam_kernel<<<dim3(CRF_B / 16, S), dim3(64), 0, stream>>>(
        pad_x, trans, orig, ws_v, ws_u, S, L);
    crf_stitch_kernel<<<dim3(CRF_B / 64), dim3(64), 0, stream>>>(
        ws_v, ws_u, ws_c, S);
    crf_out_kernel<<<dim3(CRF_B / 16, S), dim3(64), 0, stream>>>(
        pad_x, trans, orig, ws_v, ws_c, out, S, L);
}

// Round 7
// 55.286 us; speedup vs baseline: 3.7776x; 1.1427x over previous
//
#include <hip/hip_runtime.h>
#include <hip/hip_bf16.h>

#define CRF_B 1024
#define CRF_T 512
#define CRF_C 32
#define SEG_S 32          // seam segments
#define SEG_L 16          // timesteps per seam segment
#define WARM  8           // warmup steps (Birkhoff: err <= 2*0.462^7 ~ 0.009)

typedef float f32x4 __attribute__((ext_vector_type(4)));
typedef short s16x8 __attribute__((ext_vector_type(8)));

// f32 -> bf16 bits, round-nearest-even (init/const path only)
static __device__ __forceinline__ unsigned f2bf(float f) {
    union { float f; unsigned u; } v; v.f = f;
    return (v.u + 0x7FFFu + ((v.u >> 16) & 1u)) >> 16;
}

#define CVT_PK(dst, lo, hi) \
    asm("v_cvt_pk_bf16_f32 %0, %1, %2" : "=v"(dst) : "v"(lo), "v"(hi))
#define SWAP32(a, b) \
    asm("v_permlane32_swap_b32 %0, %1" : "+v"(a), "+v"(b))
#define SWAP16(a, b) \
    asm("v_permlane16_swap_b32 %0, %1" : "+v"(a), "+v"(b))

#define MAKE_AFRAGS()                                                          \
    s16x8 A0, A1;                                                              \
    _Pragma("unroll")                                                          \
    for (int e = 0; e < 8; ++e) {                                              \
        int k_ = h * 8 + e;                                                    \
        A0[e] = (short)f2bf(__expf(trans[r * CRF_C + k_]));                    \
        A1[e] = (short)f2bf(__expf(trans[(16 + r) * CRF_C + k_]));             \
    }

#define LOADSLOT(PL_, PH_, TT_)                                                \
    { const float* pa_ = xb + (size_t)(TT_) * CRF_C;                           \
      PL_ = *(const f32x4*)(pa_ + 4 * h);                                      \
      PH_ = *(const f32x4*)(pa_ + 16 + 4 * h); }

// ============================================================================
// Pass 1 (seam): per (batch16-group, segment) run spec chain from flat init at
// 16*s - WARM (s=0: exact from t=0). Exponent rescale, no on-chain logs.
// Stores converged spec-alpha snapshots at t = CPL*zz - 1 for the zz's this
// segment owns (snap[(b*zzn+zz)*32 + j], f32), plus ws_u[b*32+s] =
// spec-alpha[16*(s+1)-1][0].
// ============================================================================
__global__ __launch_bounds__(64) void crf_seam_kernel(
    const float* __restrict__ x, const float* __restrict__ trans,
    const float* __restrict__ orig, float* __restrict__ snap,
    float* __restrict__ ws_u, int CPL)
{
    const int l = threadIdx.x;
    const int r = l & 15;
    const int h = l >> 4;
    const int b = blockIdx.x * 16 + r;
    const int s = blockIdx.y;
    const int zzn = CRF_T / CPL;

    MAKE_AFRAGS();

    const float* xb = x + (size_t)b * CRF_T * CRF_C;
    const int t_a    = (s == 0) ? 0 : (SEG_L * s - WARM);
    const int nsteps = (s == 0) ? (SEG_L - 1) : (SEG_L + WARM - 1);
    const int tend   = t_a + nsteps;      // last x row needed

    // checkpoint schedule
    int kck, zzck, nck;
    if (s == 0) {
        if (CPL == 8) { kck = 7; zzck = 1; nck = 1; }
        else          { kck = 1 << 30; zzck = 0; nck = 0; }
    } else {
        kck = WARM - 1; zzck = s * (SEG_L / CPL); nck = SEG_L / CPL;
    }

    // init state at t_a
    float base0;
    f32x4 ab0, ab1;
    {
        const float* row = xb + (size_t)t_a * CRF_C;
        ab0 = *(const f32x4*)(row + 8 * h);
        ab1 = *(const f32x4*)(row + 8 * h + 4);
        if (s == 0) {
            f32x4 ob0 = *(const f32x4*)(orig + 8 * h);
            f32x4 ob1 = *(const f32x4*)(orig + 8 * h + 4);
            #pragma unroll
            for (int i = 0; i < 4; ++i) { ab0[i] += ob0[i]; ab1[i] += ob1[i]; }
            base0 = row[0] + orig[0];
        } else {
            base0 = row[0];
        }
    }
    float A = base0;   // alpha ~= log(p) + A
    s16x8 Bf;
    {
        unsigned q0, q1, q2, q3;
        CVT_PK(q0, __expf(ab0[0] - base0), __expf(ab0[1] - base0));
        CVT_PK(q1, __expf(ab0[2] - base0), __expf(ab0[3] - base0));
        CVT_PK(q2, __expf(ab1[0] - base0), __expf(ab1[1] - base0));
        CVT_PK(q3, __expf(ab1[2] - base0), __expf(ab1[3] - base0));
        union { unsigned w[4]; s16x8 v; } bu;
        bu.w[0] = q0; bu.w[1] = q1; bu.w[2] = q2; bu.w[3] = q3;
        Bf = bu.v;
    }

    f32x4 pl0, pl1, pl2, pl3, qh0, qh1, qh2, qh3;
    LOADSLOT(pl0, qh0, t_a + 1) LOADSLOT(pl1, qh1, t_a + 2)
    LOADSLOT(pl2, qh2, t_a + 3) LOADSLOT(pl3, qh3, t_a + 4)

    const f32x4 zz4 = {0.f, 0.f, 0.f, 0.f};
    int t = t_a + 1, k = 1;
    float uval = 0.0f;

#define PSTEP(PL_, PH_)                                                        \
    {                                                                          \
        f32x4 xl = PL_, xh = PH_;                                              \
        { int tn_ = t + 4; if (tn_ > tend) tn_ = tend;                         \
          LOADSLOT(PL_, PH_, tn_) }                                            \
        f32x4 D0 = __builtin_amdgcn_mfma_f32_16x16x32_bf16(A0, Bf, zz4, 0, 0, 0); \
        f32x4 D1 = __builtin_amdgcn_mfma_f32_16x16x32_bf16(A1, Bf, zz4, 0, 0, 0); \
        int ex = (int)((__float_as_uint(D0[0]) >> 23) & 0xFFu) - 127;          \
        ex = __shfl(ex, r, 64);                                                \
        float me = (float)ex;                                                  \
        float Aent = A;                                                        \
        A = Aent + me * 0.69314718055994530942f;                               \
        float f0 = exp2f(fmaf(xl[0], 1.44269504088896f, -me));                 \
        float f1 = exp2f(fmaf(xl[1], 1.44269504088896f, -me));                 \
        float f2 = exp2f(fmaf(xl[2], 1.44269504088896f, -me));                 \
        float f3 = exp2f(fmaf(xl[3], 1.44269504088896f, -me));                 \
        float g0 = exp2f(fmaf(xh[0], 1.44269504088896f, -me));                 \
        float g1 = exp2f(fmaf(xh[1], 1.44269504088896f, -me));                 \
        float g2 = exp2f(fmaf(xh[2], 1.44269504088896f, -me));                 \
        float g3 = exp2f(fmaf(xh[3], 1.44269504088896f, -me));                 \
        if (nck > 0 && k == kck) {   /* converged snapshot at t = CPL*zzck-1 */\
            f32x4 vlo, vhi;                                                    \
            vlo[0] = xl[0] + Aent + __logf(D0[0]);                             \
            vlo[1] = xl[1] + Aent + __logf(D0[1]);                             \
            vlo[2] = xl[2] + Aent + __logf(D0[2]);                             \
            vlo[3] = xl[3] + Aent + __logf(D0[3]);                             \
            vhi[0] = xh[0] + Aent + __logf(D1[0]);                             \
            vhi[1] = xh[1] + Aent + __logf(D1[1]);                             \
            vhi[2] = xh[2] + Aent + __logf(D1[2]);                             \
            vhi[3] = xh[3] + Aent + __logf(D1[3]);                             \
            float* vrow = snap + ((size_t)b * zzn + zzck) * CRF_C;             \
            *(f32x4*)(vrow + 4 * h) = vlo;                                     \
            *(f32x4*)(vrow + 16 + 4 * h) = vhi;                                \
            kck += CPL; ++zzck; --nck;                                         \
        }                                                                      \
        if (k == nsteps) uval = xl[0] + Aent + __logf(D0[0]);                  \
        unsigned w0, w1, w2, w3;                                               \
        CVT_PK(w0, D0[0] * f0, D0[1] * f1);                                    \
        CVT_PK(w1, D0[2] * f2, D0[3] * f3);                                    \
        CVT_PK(w2, D1[0] * g0, D1[1] * g1);                                    \
        CVT_PK(w3, D1[2] * g2, D1[3] * g3);                                    \
        SWAP32(w0, w2); SWAP16(w0, w2);                                        \
        SWAP32(w1, w3); SWAP16(w1, w3);                                        \
        {                                                                      \
            union { unsigned w[4]; s16x8 v; } bu_;                             \
            bu_.w[0] = w0; bu_.w[1] = w1; bu_.w[2] = w2; bu_.w[3] = w3;        \
            Bf = bu_.v;                                                        \
        }                                                                      \
        ++t; ++k;                                                              \
    }

    const int ngr = nsteps >> 2;    // nsteps = 15 or 23, both == 3 (mod 4)
    for (int g = 0; g < ngr; ++g) {
        PSTEP(pl0, qh0) PSTEP(pl1, qh1) PSTEP(pl2, qh2) PSTEP(pl3, qh3)
    }
    PSTEP(pl0, qh0) PSTEP(pl1, qh1) PSTEP(pl2, qh2)
#undef PSTEP

    if (h == 0) ws_u[(size_t)b * SEG_S + s] = uval;
}

// ============================================================================
// Pass 2 (stitch): per-batch serial prefix of segment offsets.
// c_0 = 0;  c_s = c_{s-1} + u_{s-1} - v0_s, v0_s = snap[(b*zzn + s*zst)*32]
// ============================================================================
__global__ __launch_bounds__(64) void crf_stitch_kernel(
    const float* __restrict__ snap, const float* __restrict__ ws_u,
    float* __restrict__ ws_c, int CPL)
{
    int b = blockIdx.x * 64 + threadIdx.x;
    const int zzn = CRF_T / CPL, zst = SEG_L / CPL;
    float c = 0.0f;
    ws_c[(size_t)b * SEG_S] = 0.0f;
    for (int s = 1; s < SEG_S; ++s) {
        c += ws_u[(size_t)b * SEG_S + s - 1]
           - snap[((size_t)b * zzn + (size_t)s * zst) * CRF_C];
        ws_c[(size_t)b * SEG_S + s] = c;
    }
}

// ============================================================================
// Pass 3 (out): per (batch16-group, checkpoint zz) exact outputs.
// zz=0: exact init at t=0 (writes t=0, then CPL-1 steps).
// zz>0: init from snap[b][zz] (+ c of enclosing segment), CPL steps.
// ============================================================================
__global__ __launch_bounds__(64) void crf_out_kernel(
    const float* __restrict__ x, const float* __restrict__ trans,
    const float* __restrict__ orig, const float* __restrict__ snap,
    const float* __restrict__ ws_c, float* __restrict__ out, int CPL)
{
    const int l = threadIdx.x;
    const int r = l & 15;
    const int h = l >> 4;
    const int b = blockIdx.x * 16 + r;
    const int zz = blockIdx.y;
    const int zzn = CRF_T / CPL;

    MAKE_AFRAGS();

    const float* xb = x + (size_t)b * CRF_T * CRF_C;

    int t0, nst;
    float s0;
    s16x8 Bf;
    if (zz == 0) {
        t0 = 1; nst = CPL - 1;
        s0 = xb[0] + orig[0];
        f32x4 ib0 = *(const f32x4*)(xb + 8 * h);
        f32x4 ib1 = *(const f32x4*)(xb + 8 * h + 4);
        f32x4 ob0 = *(const f32x4*)(orig + 8 * h);
        f32x4 ob1 = *(const f32x4*)(orig + 8 * h + 4);
        unsigned q0, q1, q2, q3;
        CVT_PK(q0, __expf(ib0[0] + ob0[0] - s0), __expf(ib0[1] + ob0[1] - s0));
        CVT_PK(q1, __expf(ib0[2] + ob0[2] - s0), __expf(ib0[3] + ob0[3] - s0));
        CVT_PK(q2, __expf(ib1[0] + ob1[0] - s0), __expf(ib1[1] + ob1[1] - s0));
        CVT_PK(q3, __expf(ib1[2] + ob1[2] - s0), __expf(ib1[3] + ob1[3] - s0));
        union { unsigned w[4]; s16x8 v; } bu;
        bu.w[0] = q0; bu.w[1] = q1; bu.w[2] = q2; bu.w[3] = q3;
        Bf = bu.v;
        // t = 0 outputs (D-layout)
        f32x4 xd0 = *(const f32x4*)(xb + 4 * h);
        f32x4 xd1 = *(const f32x4*)(xb + 16 + 4 * h);
        f32x4 od0 = *(const f32x4*)(orig + 4 * h);
        f32x4 od1 = *(const f32x4*)(orig + 16 + 4 * h);
        f32x4 a00, a01;
        #pragma unroll
        for (int i = 0; i < 4; ++i) { a00[i] = xd0[i] + od0[i]; a01[i] = xd1[i] + od1[i]; }
        *(f32x4*)(out + (size_t)b * CRF_C + 4 * h) = a00;
        *(f32x4*)(out + (size_t)b * CRF_C + 16 + 4 * h) = a01;
    } else {
        t0 = zz * CPL; nst = CPL;
        const int s_seg = (zz * CPL) >> 4;          // enclosing seam segment
        const float cc = ws_c[(size_t)b * SEG_S + s_seg];
        const float* vp = snap + ((size_t)b * zzn + zz) * CRF_C;
        const float vp0 = vp[0];
        s0 = vp0 + cc;
        f32x4 vb0 = *(const f32x4*)(vp + 8 * h);
        f32x4 vb1 = *(const f32x4*)(vp + 8 * h + 4);
        unsigned q0, q1, q2, q3;                     // note: cc cancels in state
        CVT_PK(q0, __expf(vb0[0] - vp0), __expf(vb0[1] - vp0));
        CVT_PK(q1, __expf(vb0[2] - vp0), __expf(vb0[3] - vp0));
        CVT_PK(q2, __expf(vb1[0] - vp0), __expf(vb1[1] - vp0));
        CVT_PK(q3, __expf(vb1[2] - vp0), __expf(vb1[3] - vp0));
        union { unsigned w[4]; s16x8 v; } bu;
        bu.w[0] = q0; bu.w[1] = q1; bu.w[2] = q2; bu.w[3] = q3;
        Bf = bu.v;
    }
    const int tendo = zz * CPL + CPL - 1;           // last x row this block needs

    f32x4 pl0, pl1, pl2, pl3, qh0, qh1, qh2, qh3;
    LOADSLOT(pl0, qh0, t0)     LOADSLOT(pl1, qh1, t0 + 1)
    LOADSLOT(pl2, qh2, t0 + 2) LOADSLOT(pl3, qh3, t0 + 3)

    const f32x4 zz4 = {0.f, 0.f, 0.f, 0.f};
    float sU = s0, sC = s0, aQ = s0;
    float* op0 = out + ((size_t)t0 * CRF_B + b) * CRF_C + 4 * h;
    int t = t0;

#define STEP(PL_, PH_)                                                         \
    {                                                                          \
        f32x4 xl = PL_, xh = PH_;                                              \
        { int tn_ = t + 4; if (tn_ > tendo) tn_ = tendo;                       \
          LOADSLOT(PL_, PH_, tn_) }                                            \
        f32x4 D0 = __builtin_amdgcn_mfma_f32_16x16x32_bf16(A0, Bf, zz4, 0, 0, 0); \
        f32x4 D1 = __builtin_amdgcn_mfma_f32_16x16x32_bf16(A1, Bf, zz4, 0, 0, 0); \
        float dlt = sU - sC;                                                   \
        float f0 = __expf(xl[0] + dlt), f1 = __expf(xl[1] + dlt);              \
        float f2 = __expf(xl[2] + dlt), f3 = __expf(xl[3] + dlt);              \
        float g0 = __expf(xh[0] + dlt), g1 = __expf(xh[1] + dlt);              \
        float g2 = __expf(xh[2] + dlt), g3 = __expf(xh[3] + dlt);              \
        f32x4 alo, ahi;                                                        \
        alo[0] = xl[0] + sU + __logf(D0[0]);                                   \
        alo[1] = xl[1] + sU + __logf(D0[1]);                                   \
        alo[2] = xl[2] + sU + __logf(D0[2]);                                   \
        alo[3] = xl[3] + sU + __logf(D0[3]);                                   \
        ahi[0] = xh[0] + sU + __logf(D1[0]);                                   \
        ahi[1] = xh[1] + sU + __logf(D1[1]);                                   \
        ahi[2] = xh[2] + sU + __logf(D1[2]);                                   \
        ahi[3] = xh[3] + sU + __logf(D1[3]);                                   \
        *(f32x4*)op0 = alo;                                                    \
        *(f32x4*)(op0 + 16) = ahi;                                             \
        op0 += (size_t)CRF_B * CRF_C;                                          \
        float a0new = __shfl(alo[0], r, 64);                                   \
        unsigned w0, w1, w2, w3;                                               \
        CVT_PK(w0, D0[0] * f0, D0[1] * f1);                                    \
        CVT_PK(w1, D0[2] * f2, D0[3] * f3);                                    \
        CVT_PK(w2, D1[0] * g0, D1[1] * g1);                                    \
        CVT_PK(w3, D1[2] * g2, D1[3] * g3);                                    \
        SWAP32(w0, w2); SWAP16(w0, w2);                                        \
        SWAP32(w1, w3); SWAP16(w1, w3);                                        \
        {                                                                      \
            union { unsigned w[4]; s16x8 v; } bu_;                             \
            bu_.w[0] = w0; bu_.w[1] = w1; bu_.w[2] = w2; bu_.w[3] = w3;        \
            Bf = bu_.v;                                                        \
        }                                                                      \
        sU = sC; sC = aQ; aQ = a0new;                                          \
        ++t;                                                                   \
    }

    const int ngr = nst >> 2;
    for (int g = 0; g < ngr; ++g) {
        STEP(pl0, qh0) STEP(pl1, qh1) STEP(pl2, qh2) STEP(pl3, qh3)
    }
    if (nst & 3) {    // tail is 0 or 3
        STEP(pl0, qh0) STEP(pl1, qh1) STEP(pl2, qh2)
    }
#undef STEP
}

// ============================================================================
// Fallback (round-5 single-kernel, validated) — used only if ws too small.
// ============================================================================
__global__ __launch_bounds__(64) void crf_fwd_fallback(
    const float* __restrict__ x, const float* __restrict__ trans,
    const float* __restrict__ orig, float* __restrict__ out)
{
    const int l = threadIdx.x;
    const int r = l & 15;
    const int h = l >> 4;
    const int b = blockIdx.x * 16 + r;

    MAKE_AFRAGS();

    const float* xb = x + (size_t)b * CRF_T * CRF_C;
    float s0 = xb[0] + orig[0];

    f32x4 ib0 = *(const f32x4*)(xb + 8 * h);
    f32x4 ib1 = *(const f32x4*)(xb + 8 * h + 4);
    f32x4 ob0 = *(const f32x4*)(orig + 8 * h);
    f32x4 ob1 = *(const f32x4*)(orig + 8 * h + 4);
    unsigned q0, q1, q2, q3;
    CVT_PK(q0, __expf(ib0[0] + ob0[0] - s0), __expf(ib0[1] + ob0[1] - s0));
    CVT_PK(q1, __expf(ib0[2] + ob0[2] - s0), __expf(ib0[3] + ob0[3] - s0));
    CVT_PK(q2, __expf(ib1[0] + ob1[0] - s0), __expf(ib1[1] + ob1[1] - s0));
    CVT_PK(q3, __expf(ib1[2] + ob1[2] - s0), __expf(ib1[3] + ob1[3] - s0));
    s16x8 Bf;
    {
        union { unsigned w[4]; s16x8 v; } bu;
        bu.w[0] = q0; bu.w[1] = q1; bu.w[2] = q2; bu.w[3] = q3;
        Bf = bu.v;
    }
    {
        f32x4 xd0 = *(const f32x4*)(xb + 4 * h);
        f32x4 xd1 = *(const f32x4*)(xb + 16 + 4 * h);
        f32x4 od0 = *(const f32x4*)(orig + 4 * h);
        f32x4 od1 = *(const f32x4*)(orig + 16 + 4 * h);
        f32x4 a00, a01;
        #pragma unroll
        for (int i = 0; i < 4; ++i) { a00[i] = xd0[i] + od0[i]; a01[i] = xd1[i] + od1[i]; }
        *(f32x4*)(out + (size_t)b * CRF_C + 4 * h) = a00;
        *(f32x4*)(out + (size_t)b * CRF_C + 16 + 4 * h) = a01;
    }

    f32x4 pl0, pl1, pl2, pl3, qh0, qh1, qh2, qh3;
    LOADSLOT(pl0, qh0, 1) LOADSLOT(pl1, qh1, 2)
    LOADSLOT(pl2, qh2, 3) LOADSLOT(pl3, qh3, 4)

    const f32x4 zz4 = {0.f, 0.f, 0.f, 0.f};
    float sU = s0, sC = s0, aQ = s0;
    float* op0 = out + ((size_t)CRF_B + b) * CRF_C + 4 * h;
    int t = 1;

#define STEP(PL_, PH_)                                                         \
    {                                                                          \
        f32x4 xl = PL_, xh = PH_;                                              \
        { int tn_ = t + 4; if (tn_ > CRF_T - 1) tn_ = CRF_T - 1;               \
          LOADSLOT(PL_, PH_, tn_) }                                            \
        f32x4 D0 = __builtin_amdgcn_mfma_f32_16x16x32_bf16(A0, Bf, zz4, 0, 0, 0); \
        f32x4 D1 = __builtin_amdgcn_mfma_f32_16x16x32_bf16(A1, Bf, zz4, 0, 0, 0); \
        float dlt = sU - sC;                                                   \
        float f0 = __expf(xl[0] + dlt), f1 = __expf(xl[1] + dlt);              \
        float f2 = __expf(xl[2] + dlt), f3 = __expf(xl[3] + dlt);              \
        float g0 = __expf(xh[0] + dlt), g1 = __expf(xh[1] + dlt);              \
        float g2 = __expf(xh[2] + dlt), g3 = __expf(xh[3] + dlt);              \
        f32x4 alo, ahi;                                                        \
        alo[0] = xl[0] + sU + __logf(D0[0]);                                   \
        alo[1] = xl[1] + sU + __logf(D0[1]);                                   \
        alo[2] = xl[2] + sU + __logf(D0[2]);                                   \
        alo[3] = xl[3] + sU + __logf(D0[3]);                                   \
        ahi[0] = xh[0] + sU + __logf(D1[0]);                                   \
        ahi[1] = xh[1] + sU + __logf(D1[1]);                                   \
        ahi[2] = xh[2] + sU + __logf(D1[2]);                                   \
        ahi[3] = xh[3] + sU + __logf(D1[3]);                                   \
        *(f32x4*)op0 = alo;                                                    \
        *(f32x4*)(op0 + 16) = ahi;                                             \
        op0 += (size_t)CRF_B * CRF_C;                                          \
        float a0new = __shfl(alo[0], r, 64);                                   \
        unsigned w0, w1, w2, w3;                                               \
        CVT_PK(w0, D0[0] * f0, D0[1] * f1);                                    \
        CVT_PK(w1, D0[2] * f2, D0[3] * f3);                                    \
        CVT_PK(w2, D1[0] * g0, D1[1] * g1);                                    \
        CVT_PK(w3, D1[2] * g2, D1[3] * g3);                                    \
        SWAP32(w0, w2); SWAP16(w0, w2);                                        \
        SWAP32(w1, w3); SWAP16(w1, w3);                                        \
        {                                                                      \
            union { unsigned w[4]; s16x8 v; } bu_;                             \
            bu_.w[0] = w0; bu_.w[1] = w1; bu_.w[2] = w2; bu_.w[3] = w3;        \
            Bf = bu_.v;                                                        \
        }                                                                      \
        sU = sC; sC = aQ; aQ = a0new;                                          \
        ++t;                                                                   \
    }

    for (int g = 0; g < 127; ++g) {   // 508 steps
        STEP(pl0, qh0) STEP(pl1, qh1) STEP(pl2, qh2) STEP(pl3, qh3)
    }
    STEP(pl0, qh0) STEP(pl1, qh1) STEP(pl2, qh2)   // 511 total
#undef STEP
}

extern "C" void kernel_launch(void* const* d_in, const int* in_sizes, int n_in,
                              void* d_out, int out_size, void* d_ws, size_t ws_size,
                              hipStream_t stream) {
    const float* pad_x = (const float*)d_in[0];
    const float* trans = (const float*)d_in[1];
    const float* orig  = (const float*)d_in[2];
    float* out = (float*)d_out;

    const size_t uc_bytes = (size_t)CRF_B * SEG_S * sizeof(float);   // u or c
    const size_t snap8  = (size_t)CRF_B * 64 * CRF_C * sizeof(float); // 8 MB
    const size_t snap16 = (size_t)CRF_B * 32 * CRF_C * sizeof(float); // 4 MB

    int CPL = 0;
    if (ws_size >= snap8 + 2 * uc_bytes)       CPL = 8;
    else if (ws_size >= snap16 + 2 * uc_bytes) CPL = 16;

    if (CPL == 0) {
        crf_fwd_fallback<<<dim3(CRF_B / 16), dim3(64), 0, stream>>>(
            pad_x, trans, orig, out);
        return;
    }
    const int zzn = CRF_T / CPL;
    float* snap = (float*)d_ws;
    float* ws_u = snap + (size_t)CRF_B * zzn * CRF_C;
    float* ws_c = ws_u + (size_t)CRF_B * SEG_S;

    crf_seam_kernel<<<dim3(CRF_B / 16, SEG_S), dim3(64), 0, stream>>>(
        pad_x, trans, orig, snap, ws_u, CPL);
    crf_stitch_kernel<<<dim3(CRF_B / 64), dim3(64), 0, stream>>>(
        snap, ws_u, ws_c, CPL);
    crf_out_kernel<<<dim3(CRF_B / 16, zzn), dim3(64), 0, stream>>>(
        pad_x, trans, orig, snap, ws_c, out, CPL);
}